// Round 9
// baseline (758.205 us; speedup 1.0000x reference)
//
#include <hip/hip_runtime.h>
#include <hip/hip_bf16.h>

#define N_NODES 100000
#define N_EDGES 1600000
#define DD 128
#define N_GRAPHS 512
#define BN_EPS 1e-5f
#define NTILES 3125            // 3125*32 == 100000 exactly: no partial tiles
#define SCAN_B 98              // ceil(100000/1024)
#define RED_B 25               // 3125 = 25 * 125
#define PART_N 12500           // N_NODES / 8 (per-XCD node slice)

typedef unsigned int u32;
typedef unsigned char u8;
typedef __bf16 bf16_t;
typedef __bf16 bf16x2 __attribute__((ext_vector_type(2)));
typedef __bf16 bf16x4 __attribute__((ext_vector_type(4)));
typedef __bf16 bf16x8 __attribute__((ext_vector_type(8)));
typedef float f32x4 __attribute__((ext_vector_type(4)));

__device__ __forceinline__ u32 pack4u(float v0, float v1, float v2, float v3, float inv) {
    u32 q0 = (u32)fminf(rintf(v0 * inv), 255.f);
    u32 q1 = (u32)fminf(rintf(v1 * inv), 255.f);
    u32 q2 = (u32)fminf(rintf(v2 * inv), 255.f);
    u32 q3 = (u32)fminf(rintf(v3 * inv), 255.f);
    return q0 | (q1 << 8) | (q2 << 16) | (q3 << 24);
}

// ---------------- utility kernels ----------------

__global__ void k_zero(float4* p, int n) {
    float4 z = make_float4(0.f, 0.f, 0.f, 0.f);
    for (int i = blockIdx.x * blockDim.x + threadIdx.x; i < n; i += gridDim.x * blockDim.x)
        p[i] = z;
}

// XCD-partitioned histogram with NON-TEMPORAL edge reads.
__global__ void k_hist8(const int* __restrict__ dst, int* __restrict__ deg) {
    const int part = blockIdx.x & 7;
    const int lo = part * PART_N, hi = lo + PART_N;
    const int start = (blockIdx.x >> 3) * blockDim.x + threadIdx.x;
    const int stride = (gridDim.x >> 3) * blockDim.x;
    for (int e = start; e < N_EDGES; e += stride) {
        int d = __builtin_nontemporal_load(dst + e);
        if (d >= lo && d < hi) atomicAdd(&deg[d], 1);
    }
}

// hierarchical scan of padded degrees ((deg+3)&~3) -> poffs, cursor
__global__ void k_scan1(const int* __restrict__ deg, int* __restrict__ bsum) {
    __shared__ int sh[1024];
    int b = blockIdx.x, t = threadIdx.x;
    int i = b * 1024 + t;
    int pd = (i < N_NODES) ? ((deg[i] + 3) & ~3) : 0;
    sh[t] = pd;
    __syncthreads();
    for (int s = 512; s > 0; s >>= 1) {
        if (t < s) sh[t] += sh[t + s];
        __syncthreads();
    }
    if (t == 0) bsum[b] = sh[0];
}
__global__ void k_scan2(const int* __restrict__ bsum, int* __restrict__ bbase,
                        int* __restrict__ poffs) {
    __shared__ int sh[128];
    int t = threadIdx.x;
    int v = (t < SCAN_B) ? bsum[t] : 0;
    sh[t] = v;
    __syncthreads();
    for (int d = 1; d < 128; d <<= 1) {
        int o = (t >= d) ? sh[t - d] : 0;
        __syncthreads();
        sh[t] += o;
        __syncthreads();
    }
    if (t < SCAN_B) bbase[t] = sh[t] - v;          // exclusive base per block
    if (t == SCAN_B - 1) poffs[N_NODES] = sh[t];   // total padded edges
}
__global__ void k_scan3(const int* __restrict__ deg, const int* __restrict__ bbase,
                        int* __restrict__ poffs, int* __restrict__ cursor) {
    __shared__ int sh[1024];
    int b = blockIdx.x, t = threadIdx.x;
    int i = b * 1024 + t;
    int pd = (i < N_NODES) ? ((deg[i] + 3) & ~3) : 0;
    sh[t] = pd;
    __syncthreads();
    for (int d = 1; d < 1024; d <<= 1) {
        int o = (t >= d) ? sh[t - d] : 0;
        __syncthreads();
        sh[t] += o;
        __syncthreads();
    }
    if (i < N_NODES) {
        int off = bbase[b] + sh[t] - pd;
        poffs[i] = off; cursor[i] = off;
    }
}

// XCD-partitioned fill with NON-TEMPORAL dst/src reads.
__global__ void k_fill8(const int* __restrict__ src, const int* __restrict__ dst,
                        int* __restrict__ cursor, int* __restrict__ csr) {
    const int part = blockIdx.x & 7;
    const int lo = part * PART_N, hi = lo + PART_N;
    const int start = (blockIdx.x >> 3) * blockDim.x + threadIdx.x;
    const int stride = (gridDim.x >> 3) * blockDim.x;
    for (int e = start; e < N_EDGES; e += stride) {
        int d = __builtin_nontemporal_load(dst + e);
        if (d >= lo && d < hi) {
            int s = __builtin_nontemporal_load(src + e);
            int pos = atomicAdd(&cursor[d], 1);
            csr[pos] = s;
        }
    }
}

// fill pad slots with the DEST node's own index; gather subtracts the
// overcount via the self-term coefficient (1 - #pads). Self line is L1-hot.
__global__ void k_pad(const int* __restrict__ deg, const int* __restrict__ poffs,
                      int* __restrict__ csr) {
    int t = blockIdx.x * blockDim.x + threadIdx.x;
    if (t >= N_NODES * 4) return;
    int n = t >> 2, j = t & 3;
    int s = poffs[n] + deg[n];
    if (s + j < poffs[n + 1]) csr[s + j] = n;
}

// Quantize the fp32 input to EXCESS-128 u8 (stored value = q+128,
// q in [-127,127], per-row scale). The gather decodes with the cheap
// unsigned path and corrects exactly: sum s*(u-128) = sum s*u - 128*sum s.
__global__ __launch_bounds__(256) void k_cvt8(const float* __restrict__ x,
                                              u8* __restrict__ x8,
                                              float* __restrict__ xsc) {
    int wid  = (blockIdx.x * blockDim.x + threadIdx.x) >> 6;
    int lane = threadIdx.x & 63;
    int nw   = (gridDim.x * blockDim.x) >> 6;
    for (int row = wid; row < N_NODES; row += nw) {
        float2 v = *(const float2*)(x + (size_t)row * DD + lane * 2);
        float am = fmaxf(fabsf(v.x), fabsf(v.y));
#pragma unroll
        for (int o = 32; o > 0; o >>= 1) am = fmaxf(am, __shfl_xor(am, o));
        float inv = am > 0.f ? 127.f / am : 0.f;
        int q0 = (int)rintf(fminf(fmaxf(v.x * inv, -127.f), 127.f)) + 128;
        int q1 = (int)rintf(fminf(fmaxf(v.y * inv, -127.f), 127.f)) + 128;
        u32 pk = ((u32)q0 & 0xff) | (((u32)q1 & 0xff) << 8);
        *(unsigned short*)(x8 + (size_t)row * DD + lane * 2) = (unsigned short)pk;
        if (lane == 0) xsc[row] = am * (1.f / 127.f);
    }
}

// Pre-shuffle the 6 weight matrices into exact MFMA B-fragment order (bf16).
__global__ void k_shufw(const float* __restrict__ W1s, const float* __restrict__ W2s,
                        bf16_t* __restrict__ wshuf) {
    int t = blockIdx.x * blockDim.x + threadIdx.x;
    if (t >= 6 * 16384) return;
    int g  = t >> 14;
    int r  = t & 16383;
    int j  = r & 7;
    int L  = (r >> 3) & 63;
    int nt = (r >> 9) & 7;
    int ks = r >> 12;
    int l  = g >> 1;
    const float* src = (g & 1) ? (W2s + l * 16384) : (W1s + l * 16384);
    int k = ks * 32 + (L >> 4) * 8 + j;
    int n = nt * 16 + (L & 15);
    wshuf[t] = (bf16_t)src[k * DD + n];
}

__global__ void k_aff_init(float* __restrict__ ss) {
    int f = threadIdx.x;
    if (f < DD) { ss[f] = 1.0f; ss[DD + f] = 0.0f; }
}

// stage-2 reduction of per-block partial stats: 25 blocks x 125 rows
__global__ void k_red(const float* __restrict__ pstats, float* __restrict__ red) {
    int b = blockIdx.x;            // 0..24
    int t = threadIdx.x;           // 0..255
    const float* p = pstats + (size_t)b * 125 * 256 + t;
    float acc = 0.f;
    for (int i = 0; i < 125; ++i) acc += p[i * 256];
    red[b * 256 + t] = acc;
}

__global__ void k_aff_update(const float* __restrict__ red, const float* __restrict__ gamma,
                             const float* __restrict__ beta, float* __restrict__ scale,
                             float* __restrict__ shift) {
    int f = threadIdx.x;
    if (f < DD) {
        float s = 0.f, q = 0.f;
        for (int i = 0; i < RED_B; ++i) {
            s += red[i * 256 + f];
            q += red[i * 256 + 128 + f];
        }
        float mu  = s * (1.0f / N_NODES);
        float var = q * (1.0f / N_NODES) - mu * mu;
        float inv = rsqrtf(var + BN_EPS);
        float sc  = gamma[f] * inv;
        scale[f] = sc;
        shift[f] = beta[f] - mu * sc;
    }
}

__global__ void k_gbounds(const int* __restrict__ batch, int* __restrict__ gstart) {
    int i = blockIdx.x * blockDim.x + threadIdx.x;
    if (i >= N_NODES) return;
    int b = batch[i];
    int bp = (i == 0) ? -1 : batch[i - 1];
    for (int g = bp + 1; g <= b; ++g) gstart[g] = i;
    if (i == N_NODES - 1)
        for (int g = b + 1; g <= N_GRAPHS; ++g) gstart[g] = N_NODES;
}

// ---------------- gather helpers ----------------
// lane = (q4, l16); lane covers features l16*8..l16*8+7 of edge csr[e+q4].
// Rows are 128B u8 (excess-128 for L0, plain u8 activations for L1/L2).

__device__ __forceinline__ uint2 load_raw(const u8* __restrict__ xg, int r, int l16) {
    return *(const uint2*)(xg + ((size_t)r << 7) + (l16 << 3));
}

// unsigned decode (v_cvt_f32_ubyte pattern) + FMA into accumulator
__device__ __forceinline__ void acc_from(uint2 d, float s, float (&a)[8]) {
    a[0] += s * (float)(d.x & 0xffu);
    a[1] += s * (float)((d.x >> 8) & 0xffu);
    a[2] += s * (float)((d.x >> 16) & 0xffu);
    a[3] += s * (float)(d.x >> 24);
    a[4] += s * (float)(d.y & 0xffu);
    a[5] += s * (float)((d.y >> 8) & 0xffu);
    a[6] += s * (float)((d.y >> 16) & 0xffu);
    a[7] += s * (float)(d.y >> 24);
}

// ---------------- fused GIN layer ----------------
// R20: QUAD-chain quarter-split gather. 4 independent nodes per wave, each a
// 1-group-at-a-time chain with wave-uniform predication -> up to 4 row loads
// in flight per iteration, and rounds per 16 rows drop from 8*E[max2(groups)]
// to 4*E[max4] (~1.75x fewer). R19's 2-group unroll failed because padded
// degree (~4-5 groups) rarely satisfied the 8-edge master condition; chains
// sidestep that (each chain advances independently). BIAS128 selects the
// excess-128 correction (L0); L1/L2 are plain u8.
template<bool BIAS128>
__global__ __launch_bounds__(128, 6) void k_layer(
    const u8* __restrict__ x8, const float* __restrict__ xsc,
    u8* __restrict__ y8, float* __restrict__ ysc,
    const int* __restrict__ poffs, const int* __restrict__ csr,
    const int* __restrict__ deg,
    const float* __restrict__ scale, const float* __restrict__ shift,
    const bf16_t* __restrict__ w1s, const bf16_t* __restrict__ w2s,
    const float* __restrict__ b1, const float* __restrict__ b2,
    float* __restrict__ pstats)
{
    __shared__ __align__(16) bf16_t tile[32 * 136];
    __shared__ float swsum[2][128];
    __shared__ float swsq[2][128];

    const int tid  = threadIdx.x;
    const int w    = tid >> 6;           // 0..1
    const int lane = tid & 63;
    const int base = blockIdx.x * 32;
    const int q4   = lane >> 4;          // quarter: edge slot / self-row owner
    const int l16  = lane & 15;          // feature octet within the row

    // ---- Phase 1: quad-chain quarter-split gather -> LDS tile ----
    for (int rp = 0; rp < 4; ++rp) {
        const int row0 = (w << 4) + rp;  // rows row0, +4, +8, +12
        int e0, e1, e2, e3, eE0, eE1, eE2, eE3;
        int r0, r1, r2, r3, dg0, dg1, dg2, dg3;
        float a0[8], a1[8], a2[8], a3[8];
        float ss0 = 0.f, ss1 = 0.f, ss2 = 0.f, ss3 = 0.f;
        {
            int n0 = base + row0, n1 = n0 + 4, n2 = n0 + 8, n3 = n0 + 12;
            e0 = poffs[n0]; eE0 = poffs[n0 + 1]; dg0 = deg[n0];
            e1 = poffs[n1]; eE1 = poffs[n1 + 1]; dg1 = deg[n1];
            e2 = poffs[n2]; eE2 = poffs[n2 + 1]; dg2 = deg[n2];
            e3 = poffs[n3]; eE3 = poffs[n3 + 1]; dg3 = deg[n3];
            r0 = csr[e0 + q4]; r1 = csr[e1 + q4];
            r2 = csr[e2 + q4]; r3 = csr[e3 + q4];
#pragma unroll
            for (int j = 0; j < 8; ++j) { a0[j] = 0.f; a1[j] = 0.f; a2[j] = 0.f; a3[j] = 0.f; }
        }

        bool c0 = e0 < eE0, c1 = e1 < eE1, c2 = e2 < eE2, c3 = e3 < eE3;
        while (c0 | c1 | c2 | c3) {
            uint2 d0, d1, d2, d3;
            float s0, s1, s2, s3;
            // issue all active loads first (up to 4 rows + 4 scales in flight)
            if (c0) { d0 = load_raw(x8, r0, l16); s0 = xsc[r0]; }
            if (c1) { d1 = load_raw(x8, r1, l16); s1 = xsc[r1]; }
            if (c2) { d2 = load_raw(x8, r2, l16); s2 = xsc[r2]; }
            if (c3) { d3 = load_raw(x8, r3, l16); s3 = xsc[r3]; }
            // prefetch next group indices (csr slack makes overread safe)
            if (c0) { e0 += 4; r0 = csr[e0 + q4]; }
            if (c1) { e1 += 4; r1 = csr[e1 + q4]; }
            if (c2) { e2 += 4; r2 = csr[e2 + q4]; }
            if (c3) { e3 += 4; r3 = csr[e3 + q4]; }
            // decode + accumulate
            if (c0) { acc_from(d0, s0, a0); if (BIAS128) ss0 += s0; }
            if (c1) { acc_from(d1, s1, a1); if (BIAS128) ss1 += s1; }
            if (c2) { acc_from(d2, s2, a2); if (BIAS128) ss2 += s2; }
            if (c3) { acc_from(d3, s3, a3); if (BIAS128) ss3 += s3; }
            c0 = e0 < eE0; c1 = e1 < eE1; c2 = e2 < eE2; c3 = e3 < eE3;
        }

        // self terms: quarter c loads node c's own row (1 instr covers 4)
        {
            int rs = base + row0 + (q4 << 2);
            uint2 d = load_raw(x8, rs, l16);
            float s = xsc[rs];
            float sc0 = 1.f - (float)(((dg0 + 3) & ~3) - dg0);
            float sc1 = 1.f - (float)(((dg1 + 3) & ~3) - dg1);
            float sc2 = 1.f - (float)(((dg2 + 3) & ~3) - dg2);
            float sc3 = 1.f - (float)(((dg3 + 3) & ~3) - dg3);
            float v[8];
            v[0] = (float)(d.x & 0xffu);
            v[1] = (float)((d.x >> 8) & 0xffu);
            v[2] = (float)((d.x >> 16) & 0xffu);
            v[3] = (float)(d.x >> 24);
            v[4] = (float)(d.y & 0xffu);
            v[5] = (float)((d.y >> 8) & 0xffu);
            v[6] = (float)((d.y >> 16) & 0xffu);
            v[7] = (float)(d.y >> 24);
            float co0 = (q4 == 0) ? sc0 * s : 0.f;
            float co1 = (q4 == 1) ? sc1 * s : 0.f;
            float co2 = (q4 == 2) ? sc2 * s : 0.f;
            float co3 = (q4 == 3) ? sc3 * s : 0.f;
#pragma unroll
            for (int j = 0; j < 8; ++j) {
                a0[j] += co0 * v[j];
                a1[j] += co1 * v[j];
                a2[j] += co2 * v[j];
                a3[j] += co3 * v[j];
            }
            if (BIAS128) { ss0 += co0; ss1 += co1; ss2 += co2; ss3 += co3; }
        }

        // combine quarters: lanes l, l^16, l^32, l^48 hold same features
#pragma unroll
        for (int j = 0; j < 8; ++j) {
            a0[j] += __shfl_xor(a0[j], 16); a0[j] += __shfl_xor(a0[j], 32);
            a1[j] += __shfl_xor(a1[j], 16); a1[j] += __shfl_xor(a1[j], 32);
            a2[j] += __shfl_xor(a2[j], 16); a2[j] += __shfl_xor(a2[j], 32);
            a3[j] += __shfl_xor(a3[j], 16); a3[j] += __shfl_xor(a3[j], 32);
        }
        if (BIAS128) {
            ss0 += __shfl_xor(ss0, 16); ss0 += __shfl_xor(ss0, 32);
            ss1 += __shfl_xor(ss1, 16); ss1 += __shfl_xor(ss1, 32);
            ss2 += __shfl_xor(ss2, 16); ss2 += __shfl_xor(ss2, 32);
            ss3 += __shfl_xor(ss3, 16); ss3 += __shfl_xor(ss3, 32);
        }

        // BN-affine + write: quarter c writes node c's row (full-wave write)
        {
            const float4 f0 = *(const float4*)(scale + (l16 << 3));
            const float4 f1 = *(const float4*)(scale + (l16 << 3) + 4);
            const float4 g0 = *(const float4*)(shift + (l16 << 3));
            const float4 g1 = *(const float4*)(shift + (l16 << 3) + 4);
            const float sarr[8] = {f0.x, f0.y, f0.z, f0.w, f1.x, f1.y, f1.z, f1.w};
            const float tarr[8] = {g0.x, g0.y, g0.z, g0.w, g1.x, g1.y, g1.z, g1.w};
            int dgsel = (q4 == 0) ? dg0 : (q4 == 1) ? dg1 : (q4 == 2) ? dg2 : dg3;
            float cnt = (float)(dgsel + 1);
            float corr = 0.f;
            if (BIAS128) {
                float sssel = (q4 == 0) ? ss0 : (q4 == 1) ? ss1 : (q4 == 2) ? ss2 : ss3;
                corr = 128.f * sssel;
            }
            const int row = row0 + (q4 << 2);
            bf16x8 pk;
#pragma unroll
            for (int j = 0; j < 8; ++j) {
                float av = ((q4 == 0) ? a0[j] : (q4 == 1) ? a1[j] : (q4 == 2) ? a2[j] : a3[j]) - corr;
                pk[j] = (bf16_t)(av * sarr[j] + cnt * tarr[j]);
            }
            *(bf16x8*)(&tile[row * 136 + (l16 << 3)]) = pk;
        }
    }
    __syncthreads();

    // ---- Phase 2: GEMM1 + bias + relu -> tile (reused) ----
    const int q = lane >> 4;
    const int c16 = lane & 15;
    const int arow = (w << 4) + c16;

    bf16x8 afr[4];
#pragma unroll
    for (int ks = 0; ks < 4; ++ks)
        afr[ks] = *(const bf16x8*)(&tile[arow * 136 + ks * 32 + q * 8]);
    __syncthreads();

    f32x4 acc[8];
#pragma unroll
    for (int nt = 0; nt < 8; ++nt) acc[nt] = (f32x4){0.f, 0.f, 0.f, 0.f};
#pragma unroll
    for (int ks = 0; ks < 4; ++ks) {
#pragma unroll
        for (int nt = 0; nt < 8; ++nt) {
            bf16x8 bfr = *(const bf16x8*)(w1s + (((ks << 3) + nt) * 64 + lane) * 8);
            acc[nt] = __builtin_amdgcn_mfma_f32_16x16x32_bf16(afr[ks], bfr, acc[nt], 0, 0, 0);
        }
    }
#pragma unroll
    for (int nt = 0; nt < 8; ++nt) {
        float bias = b1[(nt << 4) + c16];
#pragma unroll
        for (int i = 0; i < 4; ++i) {
            float v = fmaxf(acc[nt][i] + bias, 0.f);
            int row = (w << 4) + (q << 2) + i;
            tile[row * 136 + (nt << 4) + c16] = (bf16_t)v;
        }
    }
    __syncthreads();

    // ---- Phase 3: GEMM2 + bias + relu + BN partials -> tile ----
    bf16x8 afr2[4];
#pragma unroll
    for (int ks = 0; ks < 4; ++ks)
        afr2[ks] = *(const bf16x8*)(&tile[arow * 136 + ks * 32 + q * 8]);
    __syncthreads(); // tile overwritten below

#pragma unroll
    for (int nt = 0; nt < 8; ++nt) acc[nt] = (f32x4){0.f, 0.f, 0.f, 0.f};
#pragma unroll
    for (int ks = 0; ks < 4; ++ks) {
#pragma unroll
        for (int nt = 0; nt < 8; ++nt) {
            bf16x8 bfr = *(const bf16x8*)(w2s + (((ks << 3) + nt) * 64 + lane) * 8);
            acc[nt] = __builtin_amdgcn_mfma_f32_16x16x32_bf16(afr2[ks], bfr, acc[nt], 0, 0, 0);
        }
    }
#pragma unroll
    for (int nt = 0; nt < 8; ++nt) {
        float bias = b2[(nt << 4) + c16];
        float s1 = 0.f, s2 = 0.f;
#pragma unroll
        for (int i = 0; i < 4; ++i) {
            float v = fmaxf(acc[nt][i] + bias, 0.f);
            int row = (w << 4) + (q << 2) + i;
            s1 += v;
            s2 += v * v;
            tile[row * 136 + (nt << 4) + c16] = (bf16_t)v;
        }
        s1 += __shfl_down(s1, 32); s2 += __shfl_down(s2, 32);
        s1 += __shfl_down(s1, 16); s2 += __shfl_down(s2, 16);
        if (lane < 16) {
            swsum[w][(nt << 4) + lane] = s1;
            swsq[w][(nt << 4) + lane] = s2;
        }
    }
    __syncthreads();

    // per-block partial stats: plain coalesced stores (no atomics)
    {
        float ps = swsum[0][tid & 127] + swsum[1][tid & 127];
        float pq = swsq[0][tid & 127] + swsq[1][tid & 127];
        float* pb = pstats + (size_t)blockIdx.x * 256;
        pb[tid] = ps;          // tid in 0..127
        pb[128 + tid] = pq;
    }

    // ---- Phase 4: quantize rows -> uint8 + scale. 4 threads per row. ----
    {
        int row4 = tid >> 2, t4 = tid & 3;   // rows 0..31
        int node = base + row4;
        const bf16_t* tp = tile + row4 * 136 + t4 * 32;
        bf16x8 v0 = *(const bf16x8*)(tp);
        bf16x8 v1 = *(const bf16x8*)(tp + 8);
        bf16x8 v2 = *(const bf16x8*)(tp + 16);
        bf16x8 v3 = *(const bf16x8*)(tp + 24);
        float am = 0.f;
#pragma unroll
        for (int k = 0; k < 8; ++k) {
            am = fmaxf(am, (float)v0[k]);
            am = fmaxf(am, (float)v1[k]);
            am = fmaxf(am, (float)v2[k]);
            am = fmaxf(am, (float)v3[k]);
        }
        am = fmaxf(am, __shfl_xor(am, 1));
        am = fmaxf(am, __shfl_xor(am, 2));
        float inv = am > 0.f ? 255.f / am : 0.f;
        if (t4 == 0) ysc[node] = am * (1.f / 255.f);
        u32 u[8];
        u[0] = pack4u((float)v0[0], (float)v0[1], (float)v0[2], (float)v0[3], inv);
        u[1] = pack4u((float)v0[4], (float)v0[5], (float)v0[6], (float)v0[7], inv);
        u[2] = pack4u((float)v1[0], (float)v1[1], (float)v1[2], (float)v1[3], inv);
        u[3] = pack4u((float)v1[4], (float)v1[5], (float)v1[6], (float)v1[7], inv);
        u[4] = pack4u((float)v2[0], (float)v2[1], (float)v2[2], (float)v2[3], inv);
        u[5] = pack4u((float)v2[4], (float)v2[5], (float)v2[6], (float)v2[7], inv);
        u[6] = pack4u((float)v3[0], (float)v3[1], (float)v3[2], (float)v3[3], inv);
        u[7] = pack4u((float)v3[4], (float)v3[5], (float)v3[6], (float)v3[7], inv);
        uint4* yp = (uint4*)(y8 + (size_t)node * DD + t4 * 32);
        yp[0] = make_uint4(u[0], u[1], u[2], u[3]);
        yp[1] = make_uint4(u[4], u[5], u[6], u[7]);
    }
}

// ---------------- pooling + head ----------------

// dequantizing segmented mean-pool, 2 nodes in flight per block
__global__ __launch_bounds__(256) void k_pool2u(
    const u8* __restrict__ y8, const float* __restrict__ ysc,
    const int* __restrict__ gstart,
    const float* __restrict__ scale, const float* __restrict__ shift,
    float* __restrict__ pooled)
{
    __shared__ float part[128];
    int g = blockIdx.x;
    int t = threadIdx.x;
    int f = t & 127, h = t >> 7;
    int s = gstart[g], e = gstart[g + 1];
    float acc = 0.f;
    for (int n = s + h; n < e; n += 2)
        acc += ysc[n] * (float)y8[(size_t)n * DD + f];
    if (h == 1) part[f] = acc;
    __syncthreads();
    if (h == 0) {
        acc += part[f];
        float cnt = (float)(e - s);
        float v = acc * scale[f] + cnt * shift[f];
        pooled[g * DD + f] = v / fmaxf(cnt, 1.0f);
    }
}

__global__ void k_head(const float* __restrict__ pooled,
                       const float* __restrict__ lin1w, const float* __restrict__ lin1b,
                       const float* __restrict__ lin2w, const float* __restrict__ lin2b,
                       float* __restrict__ out) {
    __shared__ float p[DD];
    __shared__ float h[DD];
    int g = blockIdx.x;
    int t = threadIdx.x;
    p[t] = pooled[g * DD + t];
    __syncthreads();
    float a = lin1b[t];
    for (int k = 0; k < DD; ++k) a += p[k] * lin1w[k * DD + t];
    h[t] = fmaxf(a, 0.f);
    __syncthreads();
    if (t < 10) {
        float o = lin2b[t];
        for (int k = 0; k < DD; ++k) o += h[k] * lin2w[k * 10 + t];
        out[g * 10 + t] = o;
    }
}

// ---------------- launch ----------------

extern "C" void kernel_launch(void* const* d_in, const int* in_sizes, int n_in,
                              void* d_out, int out_size, void* d_ws, size_t ws_size,
                              hipStream_t stream) {
    const float* x      = (const float*)d_in[0];
    const int*   ei     = (const int*)d_in[1];
    const int*   batch  = (const int*)d_in[2];
    const float* W1s    = (const float*)d_in[3];
    const float* b1s    = (const float*)d_in[4];
    const float* W2s    = (const float*)d_in[5];
    const float* b2s    = (const float*)d_in[6];
    const float* gammas = (const float*)d_in[7];
    const float* betas  = (const float*)d_in[8];
    const float* lin1w  = (const float*)d_in[9];
    const float* lin1b  = (const float*)d_in[10];
    const float* lin2w  = (const float*)d_in[11];
    const float* lin2b  = (const float*)d_in[12];
    float* out = (float*)d_out;

    char* p = (char*)d_ws;
    size_t off = 0;
    auto alloc = [&](size_t bytes) -> char* {
        char* r = p + off;
        off += (bytes + 255) & ~(size_t)255;
        return r;
    };
    int*    deg    = (int*)alloc(N_NODES * 4);
    size_t zero_bytes = off;
    int*    poffs  = (int*)alloc((N_NODES + 1) * 4);
    int*    cursor = (int*)alloc(N_NODES * 4);
    int*    bsum   = (int*)alloc(128 * 4);
    int*    bbase  = (int*)alloc(128 * 4);
    int*    csr    = (int*)alloc(((size_t)N_EDGES + 4 * N_NODES + 64) * 4); // pad-4 + slack
    u8*     x8s    = (u8*)alloc((size_t)N_NODES * DD);   // excess-128 input; q8b aliases it after L0
    u8*     q8a    = (u8*)alloc((size_t)N_NODES * DD);
    float*  sci    = (float*)alloc(N_NODES * 4);
    float*  sca    = (float*)alloc(N_NODES * 4);
    float*  scb    = (float*)alloc(N_NODES * 4);
    bf16_t* wshuf  = (bf16_t*)alloc(6 * 16384 * 2);
    float*  ss     = (float*)alloc(4 * 256 * 4);
    int*    gstart = (int*)alloc((N_GRAPHS + 1) * 4);
    float*  pooled = (float*)alloc(N_GRAPHS * DD * 4);
    float*  pstats = (float*)alloc((size_t)NTILES * 256 * 4);    // per-block partials
    float*  red    = (float*)alloc(RED_B * 256 * 4);             // stage-2 partials
    if (off > ws_size) return;

    // q8b reuses x8s's storage: x8s is only read by L0; q8b is written by L1
    // and read by L2 (stream-ordered on one stream, no overlap).
    u8* q8b = x8s;

    const int* srcA = ei;
    const int* dstA = ei + N_EDGES;

    k_zero<<<256, 256, 0, stream>>>((float4*)d_ws, (int)(zero_bytes / 16));
    k_hist8<<<1024, 256, 0, stream>>>(dstA, deg);
    k_scan1<<<SCAN_B, 1024, 0, stream>>>(deg, bsum);
    k_scan2<<<1, 128, 0, stream>>>(bsum, bbase, poffs);
    k_scan3<<<SCAN_B, 1024, 0, stream>>>(deg, bbase, poffs, cursor);
    k_fill8<<<1024, 256, 0, stream>>>(srcA, dstA, cursor, csr);
    k_pad<<<(N_NODES * 4 + 255) / 256, 256, 0, stream>>>(deg, poffs, csr);
    k_cvt8<<<1024, 256, 0, stream>>>(x, x8s, sci);
    k_shufw<<<(6 * 16384 + 255) / 256, 256, 0, stream>>>(W1s, W2s, wshuf);
    k_aff_init<<<1, 128, 0, stream>>>(ss);
    k_gbounds<<<(N_NODES + 255) / 256, 256, 0, stream>>>(batch, gstart);

    // L0: x8s (excess-128) -> q8a. L1: q8a -> q8b (aliases x8s). L2: q8b -> q8a.
    k_layer<true><<<NTILES, 128, 0, stream>>>(
        x8s, sci, q8a, sca, poffs, csr, deg,
        ss + 0 * 256, ss + 0 * 256 + 128,
        wshuf + 0 * 16384, wshuf + 1 * 16384,
        b1s + 0 * DD, b2s + 0 * DD, pstats);
    k_red<<<RED_B, 256, 0, stream>>>(pstats, red);
    k_aff_update<<<1, 128, 0, stream>>>(red, gammas + 0 * DD, betas + 0 * DD,
                                        ss + 1 * 256, ss + 1 * 256 + 128);

    k_layer<false><<<NTILES, 128, 0, stream>>>(
        q8a, sca, q8b, scb, poffs, csr, deg,
        ss + 1 * 256, ss + 1 * 256 + 128,
        wshuf + 2 * 16384, wshuf + 3 * 16384,
        b1s + 1 * DD, b2s + 1 * DD, pstats);
    k_red<<<RED_B, 256, 0, stream>>>(pstats, red);
    k_aff_update<<<1, 128, 0, stream>>>(red, gammas + 1 * DD, betas + 1 * DD,
                                        ss + 2 * 256, ss + 2 * 256 + 128);

    k_layer<false><<<NTILES, 128, 0, stream>>>(
        q8b, scb, q8a, sca, poffs, csr, deg,
        ss + 2 * 256, ss + 2 * 256 + 128,
        wshuf + 4 * 16384, wshuf + 5 * 16384,
        b1s + 2 * DD, b2s + 2 * DD, pstats);
    k_red<<<RED_B, 256, 0, stream>>>(pstats, red);
    k_aff_update<<<1, 128, 0, stream>>>(red, gammas + 2 * DD, betas + 2 * DD,
                                        ss + 3 * 256, ss + 3 * 256 + 128);

    k_pool2u<<<N_GRAPHS, 256, 0, stream>>>(q8a, sca, gstart,
                                           ss + 3 * 256, ss + 3 * 256 + 128, pooled);
    k_head<<<N_GRAPHS, 128, 0, stream>>>(pooled, lin1w, lin1b, lin2w, lin2b, out);
}

// Round 10
// 664.620 us; speedup vs baseline: 1.1408x; 1.1408x over previous
//
#include <hip/hip_runtime.h>
#include <hip/hip_bf16.h>

#define N_NODES 100000
#define N_EDGES 1600000
#define DD 128
#define N_GRAPHS 512
#define BN_EPS 1e-5f
#define NTILES 3125            // 3125*32 == 100000 exactly: no partial tiles
#define SCAN_B 98              // ceil(100000/1024)
#define RED_B 25               // 3125 = 25 * 125
#define PART_N 12500           // N_NODES / 8 (per-XCD node slice)

typedef unsigned int u32;
typedef unsigned char u8;
typedef __bf16 bf16_t;
typedef __bf16 bf16x2 __attribute__((ext_vector_type(2)));
typedef __bf16 bf16x4 __attribute__((ext_vector_type(4)));
typedef __bf16 bf16x8 __attribute__((ext_vector_type(8)));
typedef float f32x4 __attribute__((ext_vector_type(4)));

__device__ __forceinline__ u32 pack4u(float v0, float v1, float v2, float v3, float inv) {
    u32 q0 = (u32)fminf(rintf(v0 * inv), 255.f);
    u32 q1 = (u32)fminf(rintf(v1 * inv), 255.f);
    u32 q2 = (u32)fminf(rintf(v2 * inv), 255.f);
    u32 q3 = (u32)fminf(rintf(v3 * inv), 255.f);
    return q0 | (q1 << 8) | (q2 << 16) | (q3 << 24);
}

// ---------------- utility kernels ----------------

__global__ void k_zero(float4* p, int n) {
    float4 z = make_float4(0.f, 0.f, 0.f, 0.f);
    for (int i = blockIdx.x * blockDim.x + threadIdx.x; i < n; i += gridDim.x * blockDim.x)
        p[i] = z;
}

// XCD-partitioned histogram with NON-TEMPORAL edge reads.
__global__ void k_hist8(const int* __restrict__ dst, int* __restrict__ deg) {
    const int part = blockIdx.x & 7;
    const int lo = part * PART_N, hi = lo + PART_N;
    const int start = (blockIdx.x >> 3) * blockDim.x + threadIdx.x;
    const int stride = (gridDim.x >> 3) * blockDim.x;
    for (int e = start; e < N_EDGES; e += stride) {
        int d = __builtin_nontemporal_load(dst + e);
        if (d >= lo && d < hi) atomicAdd(&deg[d], 1);
    }
}

// hierarchical scan of padded degrees ((deg+3)&~3) -> poffs, cursor
__global__ void k_scan1(const int* __restrict__ deg, int* __restrict__ bsum) {
    __shared__ int sh[1024];
    int b = blockIdx.x, t = threadIdx.x;
    int i = b * 1024 + t;
    int pd = (i < N_NODES) ? ((deg[i] + 3) & ~3) : 0;
    sh[t] = pd;
    __syncthreads();
    for (int s = 512; s > 0; s >>= 1) {
        if (t < s) sh[t] += sh[t + s];
        __syncthreads();
    }
    if (t == 0) bsum[b] = sh[0];
}
__global__ void k_scan2(const int* __restrict__ bsum, int* __restrict__ bbase,
                        int* __restrict__ poffs) {
    __shared__ int sh[128];
    int t = threadIdx.x;
    int v = (t < SCAN_B) ? bsum[t] : 0;
    sh[t] = v;
    __syncthreads();
    for (int d = 1; d < 128; d <<= 1) {
        int o = (t >= d) ? sh[t - d] : 0;
        __syncthreads();
        sh[t] += o;
        __syncthreads();
    }
    if (t < SCAN_B) bbase[t] = sh[t] - v;          // exclusive base per block
    if (t == SCAN_B - 1) poffs[N_NODES] = sh[t];   // total padded edges
}
__global__ void k_scan3(const int* __restrict__ deg, const int* __restrict__ bbase,
                        int* __restrict__ poffs, int* __restrict__ cursor) {
    __shared__ int sh[1024];
    int b = blockIdx.x, t = threadIdx.x;
    int i = b * 1024 + t;
    int pd = (i < N_NODES) ? ((deg[i] + 3) & ~3) : 0;
    sh[t] = pd;
    __syncthreads();
    for (int d = 1; d < 1024; d <<= 1) {
        int o = (t >= d) ? sh[t - d] : 0;
        __syncthreads();
        sh[t] += o;
        __syncthreads();
    }
    if (i < N_NODES) {
        int off = bbase[b] + sh[t] - pd;
        poffs[i] = off; cursor[i] = off;
    }
}

// XCD-partitioned fill with NON-TEMPORAL dst/src reads.
__global__ void k_fill8(const int* __restrict__ src, const int* __restrict__ dst,
                        int* __restrict__ cursor, int* __restrict__ csr) {
    const int part = blockIdx.x & 7;
    const int lo = part * PART_N, hi = lo + PART_N;
    const int start = (blockIdx.x >> 3) * blockDim.x + threadIdx.x;
    const int stride = (gridDim.x >> 3) * blockDim.x;
    for (int e = start; e < N_EDGES; e += stride) {
        int d = __builtin_nontemporal_load(dst + e);
        if (d >= lo && d < hi) {
            int s = __builtin_nontemporal_load(src + e);
            int pos = atomicAdd(&cursor[d], 1);
            csr[pos] = s;
        }
    }
}

// fill pad slots with the DEST node's own index; gather subtracts the
// overcount via the self-term coefficient (1 - #pads). Self line is L1-hot.
__global__ void k_pad(const int* __restrict__ deg, const int* __restrict__ poffs,
                      int* __restrict__ csr) {
    int t = blockIdx.x * blockDim.x + threadIdx.x;
    if (t >= N_NODES * 4) return;
    int n = t >> 2, j = t & 3;
    int s = poffs[n] + deg[n];
    if (s + j < poffs[n + 1]) csr[s + j] = n;
}

// Quantize the fp32 input to EXCESS-128 u8 (stored value = q+128,
// q in [-127,127], per-row scale). The gather decodes with the cheap
// unsigned path and corrects exactly: sum s*(u-128) = sum s*u - 128*sum s.
__global__ __launch_bounds__(256) void k_cvt8(const float* __restrict__ x,
                                              u8* __restrict__ x8,
                                              float* __restrict__ xsc) {
    int wid  = (blockIdx.x * blockDim.x + threadIdx.x) >> 6;
    int lane = threadIdx.x & 63;
    int nw   = (gridDim.x * blockDim.x) >> 6;
    for (int row = wid; row < N_NODES; row += nw) {
        float2 v = *(const float2*)(x + (size_t)row * DD + lane * 2);
        float am = fmaxf(fabsf(v.x), fabsf(v.y));
#pragma unroll
        for (int o = 32; o > 0; o >>= 1) am = fmaxf(am, __shfl_xor(am, o));
        float inv = am > 0.f ? 127.f / am : 0.f;
        int q0 = (int)rintf(fminf(fmaxf(v.x * inv, -127.f), 127.f)) + 128;
        int q1 = (int)rintf(fminf(fmaxf(v.y * inv, -127.f), 127.f)) + 128;
        u32 pk = ((u32)q0 & 0xff) | (((u32)q1 & 0xff) << 8);
        *(unsigned short*)(x8 + (size_t)row * DD + lane * 2) = (unsigned short)pk;
        if (lane == 0) xsc[row] = am * (1.f / 127.f);
    }
}

// Pre-shuffle the 6 weight matrices into exact MFMA B-fragment order (bf16).
__global__ void k_shufw(const float* __restrict__ W1s, const float* __restrict__ W2s,
                        bf16_t* __restrict__ wshuf) {
    int t = blockIdx.x * blockDim.x + threadIdx.x;
    if (t >= 6 * 16384) return;
    int g  = t >> 14;
    int r  = t & 16383;
    int j  = r & 7;
    int L  = (r >> 3) & 63;
    int nt = (r >> 9) & 7;
    int ks = r >> 12;
    int l  = g >> 1;
    const float* src = (g & 1) ? (W2s + l * 16384) : (W1s + l * 16384);
    int k = ks * 32 + (L >> 4) * 8 + j;
    int n = nt * 16 + (L & 15);
    wshuf[t] = (bf16_t)src[k * DD + n];
}

__global__ void k_aff_init(float* __restrict__ ss) {
    int f = threadIdx.x;
    if (f < DD) { ss[f] = 1.0f; ss[DD + f] = 0.0f; }
}

// stage-2 reduction of per-block partial stats: 25 blocks x 125 rows
__global__ void k_red(const float* __restrict__ pstats, float* __restrict__ red) {
    int b = blockIdx.x;            // 0..24
    int t = threadIdx.x;           // 0..255
    const float* p = pstats + (size_t)b * 125 * 256 + t;
    float acc = 0.f;
    for (int i = 0; i < 125; ++i) acc += p[i * 256];
    red[b * 256 + t] = acc;
}

__global__ void k_aff_update(const float* __restrict__ red, const float* __restrict__ gamma,
                             const float* __restrict__ beta, float* __restrict__ scale,
                             float* __restrict__ shift) {
    int f = threadIdx.x;
    if (f < DD) {
        float s = 0.f, q = 0.f;
        for (int i = 0; i < RED_B; ++i) {
            s += red[i * 256 + f];
            q += red[i * 256 + 128 + f];
        }
        float mu  = s * (1.0f / N_NODES);
        float var = q * (1.0f / N_NODES) - mu * mu;
        float inv = rsqrtf(var + BN_EPS);
        float sc  = gamma[f] * inv;
        scale[f] = sc;
        shift[f] = beta[f] - mu * sc;
    }
}

__global__ void k_gbounds(const int* __restrict__ batch, int* __restrict__ gstart) {
    int i = blockIdx.x * blockDim.x + threadIdx.x;
    if (i >= N_NODES) return;
    int b = batch[i];
    int bp = (i == 0) ? -1 : batch[i - 1];
    for (int g = bp + 1; g <= b; ++g) gstart[g] = i;
    if (i == N_NODES - 1)
        for (int g = b + 1; g <= N_GRAPHS; ++g) gstart[g] = N_NODES;
}

// ---------------- gather helpers ----------------
// lane = (q4, l16); lane covers features l16*8..l16*8+7 of edge csr[e+q4].
// Rows are 128B u8 (excess-128 for L0, plain u8 activations for L1/L2).

__device__ __forceinline__ uint2 load_raw(const u8* __restrict__ xg, int r, int l16) {
    return *(const uint2*)(xg + ((size_t)r << 7) + (l16 << 3));
}

// unsigned decode (v_cvt_f32_ubyte pattern) + FMA into accumulator
__device__ __forceinline__ void acc_from(uint2 d, float s, float (&a)[8]) {
    a[0] += s * (float)(d.x & 0xffu);
    a[1] += s * (float)((d.x >> 8) & 0xffu);
    a[2] += s * (float)((d.x >> 16) & 0xffu);
    a[3] += s * (float)(d.x >> 24);
    a[4] += s * (float)(d.y & 0xffu);
    a[5] += s * (float)((d.y >> 8) & 0xffu);
    a[6] += s * (float)((d.y >> 16) & 0xffu);
    a[7] += s * (float)(d.y >> 24);
}

// ---------------- fused GIN layer ----------------
// R21: quad-chain gather in BRANCH-FREE data-predicated form. R20's
// conditional-assignment CFG sent d0..d3/s0..s3 to scratch (FETCH +96MB,
// WRITE +71MB of spill traffic); here every value is unconditionally
// assigned each iteration, finished chains clamp their pointer (L1-hot
// redundant reload) and mask their contribution via zeroed scale.
// 4 independent row loads issued back-to-back per round; rounds per 16
// rows = 4*E[max4(groups)] ~ 25 vs dual's 8*E[max2] ~ 42.
template<bool BIAS128>
__global__ __launch_bounds__(128, 6) void k_layer(
    const u8* __restrict__ x8, const float* __restrict__ xsc,
    u8* __restrict__ y8, float* __restrict__ ysc,
    const int* __restrict__ poffs, const int* __restrict__ csr,
    const int* __restrict__ deg,
    const float* __restrict__ scale, const float* __restrict__ shift,
    const bf16_t* __restrict__ w1s, const bf16_t* __restrict__ w2s,
    const float* __restrict__ b1, const float* __restrict__ b2,
    float* __restrict__ pstats)
{
    __shared__ __align__(16) bf16_t tile[32 * 136];
    __shared__ float swsum[2][128];
    __shared__ float swsq[2][128];

    const int tid  = threadIdx.x;
    const int w    = tid >> 6;           // 0..1
    const int lane = tid & 63;
    const int base = blockIdx.x * 32;
    const int q4   = lane >> 4;          // quarter: edge slot / self-row owner
    const int l16  = lane & 15;          // feature octet within the row

    // ---- Phase 1: quad-chain branch-free gather -> LDS tile ----
    for (int rp = 0; rp < 4; ++rp) {
        const int row0 = (w << 4) + rp;  // rows row0, +4, +8, +12
        const int n0 = base + row0, n1 = n0 + 4, n2 = n0 + 8, n3 = n0 + 12;
        int e0 = poffs[n0], e1 = poffs[n1], e2 = poffs[n2], e3 = poffs[n3];
        const int g0 = (poffs[n0 + 1] - e0) >> 2;
        const int g1 = (poffs[n1 + 1] - e1) >> 2;
        const int g2 = (poffs[n2 + 1] - e2) >> 2;
        const int g3 = (poffs[n3 + 1] - e3) >> 2;
        const int dg0 = deg[n0], dg1 = deg[n1], dg2 = deg[n2], dg3 = deg[n3];
        const int gmax = max(max(g0, g1), max(g2, g3));

        float a0[8], a1[8], a2[8], a3[8];
#pragma unroll
        for (int j = 0; j < 8; ++j) { a0[j] = 0.f; a1[j] = 0.f; a2[j] = 0.f; a3[j] = 0.f; }
        float ss0 = 0.f, ss1 = 0.f, ss2 = 0.f, ss3 = 0.f;

        int r0 = csr[e0 + q4], r1 = csr[e1 + q4];
        int r2 = csr[e2 + q4], r3 = csr[e3 + q4];

        for (int it = 0; it < gmax; ++it) {
            // issue all 4 row loads + 4 scale loads (always; clamped chains
            // reload an L1-hot line, contribution masked below)
            uint2 d0 = load_raw(x8, r0, l16);
            uint2 d1 = load_raw(x8, r1, l16);
            uint2 d2 = load_raw(x8, r2, l16);
            uint2 d3 = load_raw(x8, r3, l16);
            float s0 = xsc[r0], s1 = xsc[r1], s2 = xsc[r2], s3 = xsc[r3];
            // advance (clamped): finished chains stay on their last group
            e0 += (it + 1 < g0) ? 4 : 0;
            e1 += (it + 1 < g1) ? 4 : 0;
            e2 += (it + 1 < g2) ? 4 : 0;
            e3 += (it + 1 < g3) ? 4 : 0;
            r0 = csr[e0 + q4]; r1 = csr[e1 + q4];
            r2 = csr[e2 + q4]; r3 = csr[e3 + q4];
            // mask finished chains via zero scale (branch-free)
            float m0 = (it < g0) ? s0 : 0.f;
            float m1 = (it < g1) ? s1 : 0.f;
            float m2 = (it < g2) ? s2 : 0.f;
            float m3 = (it < g3) ? s3 : 0.f;
            acc_from(d0, m0, a0); acc_from(d1, m1, a1);
            acc_from(d2, m2, a2); acc_from(d3, m3, a3);
            if (BIAS128) { ss0 += m0; ss1 += m1; ss2 += m2; ss3 += m3; }
        }

        // self terms: quarter c loads node c's own row (1 instr covers 4)
        {
            int rs = n0 + (q4 << 2);
            uint2 d = load_raw(x8, rs, l16);
            float s = xsc[rs];
            float sc0 = 1.f - (float)(((dg0 + 3) & ~3) - dg0);
            float sc1 = 1.f - (float)(((dg1 + 3) & ~3) - dg1);
            float sc2 = 1.f - (float)(((dg2 + 3) & ~3) - dg2);
            float sc3 = 1.f - (float)(((dg3 + 3) & ~3) - dg3);
            float v[8];
            v[0] = (float)(d.x & 0xffu);
            v[1] = (float)((d.x >> 8) & 0xffu);
            v[2] = (float)((d.x >> 16) & 0xffu);
            v[3] = (float)(d.x >> 24);
            v[4] = (float)(d.y & 0xffu);
            v[5] = (float)((d.y >> 8) & 0xffu);
            v[6] = (float)((d.y >> 16) & 0xffu);
            v[7] = (float)(d.y >> 24);
            float co0 = (q4 == 0) ? sc0 * s : 0.f;
            float co1 = (q4 == 1) ? sc1 * s : 0.f;
            float co2 = (q4 == 2) ? sc2 * s : 0.f;
            float co3 = (q4 == 3) ? sc3 * s : 0.f;
#pragma unroll
            for (int j = 0; j < 8; ++j) {
                a0[j] += co0 * v[j];
                a1[j] += co1 * v[j];
                a2[j] += co2 * v[j];
                a3[j] += co3 * v[j];
            }
            if (BIAS128) { ss0 += co0; ss1 += co1; ss2 += co2; ss3 += co3; }
        }

        // combine quarters: lanes l, l^16, l^32, l^48 hold same features
#pragma unroll
        for (int j = 0; j < 8; ++j) {
            a0[j] += __shfl_xor(a0[j], 16); a0[j] += __shfl_xor(a0[j], 32);
            a1[j] += __shfl_xor(a1[j], 16); a1[j] += __shfl_xor(a1[j], 32);
            a2[j] += __shfl_xor(a2[j], 16); a2[j] += __shfl_xor(a2[j], 32);
            a3[j] += __shfl_xor(a3[j], 16); a3[j] += __shfl_xor(a3[j], 32);
        }
        if (BIAS128) {
            ss0 += __shfl_xor(ss0, 16); ss0 += __shfl_xor(ss0, 32);
            ss1 += __shfl_xor(ss1, 16); ss1 += __shfl_xor(ss1, 32);
            ss2 += __shfl_xor(ss2, 16); ss2 += __shfl_xor(ss2, 32);
            ss3 += __shfl_xor(ss3, 16); ss3 += __shfl_xor(ss3, 32);
        }

        // BN-affine + write: quarter c writes node c's row (full-wave write)
        {
            const float4 f0 = *(const float4*)(scale + (l16 << 3));
            const float4 f1 = *(const float4*)(scale + (l16 << 3) + 4);
            const float4 g0v = *(const float4*)(shift + (l16 << 3));
            const float4 g1v = *(const float4*)(shift + (l16 << 3) + 4);
            const float sarr[8] = {f0.x, f0.y, f0.z, f0.w, f1.x, f1.y, f1.z, f1.w};
            const float tarr[8] = {g0v.x, g0v.y, g0v.z, g0v.w, g1v.x, g1v.y, g1v.z, g1v.w};
            int dgsel = (q4 == 0) ? dg0 : (q4 == 1) ? dg1 : (q4 == 2) ? dg2 : dg3;
            float cnt = (float)(dgsel + 1);
            float corr = 0.f;
            if (BIAS128) {
                float sssel = (q4 == 0) ? ss0 : (q4 == 1) ? ss1 : (q4 == 2) ? ss2 : ss3;
                corr = 128.f * sssel;
            }
            const int row = row0 + (q4 << 2);
            bf16x8 pk;
#pragma unroll
            for (int j = 0; j < 8; ++j) {
                float av = ((q4 == 0) ? a0[j] : (q4 == 1) ? a1[j] : (q4 == 2) ? a2[j] : a3[j]) - corr;
                pk[j] = (bf16_t)(av * sarr[j] + cnt * tarr[j]);
            }
            *(bf16x8*)(&tile[row * 136 + (l16 << 3)]) = pk;
        }
    }
    __syncthreads();

    // ---- Phase 2: GEMM1 + bias + relu -> tile (reused) ----
    const int q = lane >> 4;
    const int c16 = lane & 15;
    const int arow = (w << 4) + c16;

    bf16x8 afr[4];
#pragma unroll
    for (int ks = 0; ks < 4; ++ks)
        afr[ks] = *(const bf16x8*)(&tile[arow * 136 + ks * 32 + q * 8]);
    __syncthreads();

    f32x4 acc[8];
#pragma unroll
    for (int nt = 0; nt < 8; ++nt) acc[nt] = (f32x4){0.f, 0.f, 0.f, 0.f};
#pragma unroll
    for (int ks = 0; ks < 4; ++ks) {
#pragma unroll
        for (int nt = 0; nt < 8; ++nt) {
            bf16x8 bfr = *(const bf16x8*)(w1s + (((ks << 3) + nt) * 64 + lane) * 8);
            acc[nt] = __builtin_amdgcn_mfma_f32_16x16x32_bf16(afr[ks], bfr, acc[nt], 0, 0, 0);
        }
    }
#pragma unroll
    for (int nt = 0; nt < 8; ++nt) {
        float bias = b1[(nt << 4) + c16];
#pragma unroll
        for (int i = 0; i < 4; ++i) {
            float v = fmaxf(acc[nt][i] + bias, 0.f);
            int row = (w << 4) + (q << 2) + i;
            tile[row * 136 + (nt << 4) + c16] = (bf16_t)v;
        }
    }
    __syncthreads();

    // ---- Phase 3: GEMM2 + bias + relu + BN partials -> tile ----
    bf16x8 afr2[4];
#pragma unroll
    for (int ks = 0; ks < 4; ++ks)
        afr2[ks] = *(const bf16x8*)(&tile[arow * 136 + ks * 32 + q * 8]);
    __syncthreads(); // tile overwritten below

#pragma unroll
    for (int nt = 0; nt < 8; ++nt) acc[nt] = (f32x4){0.f, 0.f, 0.f, 0.f};
#pragma unroll
    for (int ks = 0; ks < 4; ++ks) {
#pragma unroll
        for (int nt = 0; nt < 8; ++nt) {
            bf16x8 bfr = *(const bf16x8*)(w2s + (((ks << 3) + nt) * 64 + lane) * 8);
            acc[nt] = __builtin_amdgcn_mfma_f32_16x16x32_bf16(afr2[ks], bfr, acc[nt], 0, 0, 0);
        }
    }
#pragma unroll
    for (int nt = 0; nt < 8; ++nt) {
        float bias = b2[(nt << 4) + c16];
        float s1 = 0.f, s2 = 0.f;
#pragma unroll
        for (int i = 0; i < 4; ++i) {
            float v = fmaxf(acc[nt][i] + bias, 0.f);
            int row = (w << 4) + (q << 2) + i;
            s1 += v;
            s2 += v * v;
            tile[row * 136 + (nt << 4) + c16] = (bf16_t)v;
        }
        s1 += __shfl_down(s1, 32); s2 += __shfl_down(s2, 32);
        s1 += __shfl_down(s1, 16); s2 += __shfl_down(s2, 16);
        if (lane < 16) {
            swsum[w][(nt << 4) + lane] = s1;
            swsq[w][(nt << 4) + lane] = s2;
        }
    }
    __syncthreads();

    // per-block partial stats: plain coalesced stores (no atomics)
    {
        float ps = swsum[0][tid & 127] + swsum[1][tid & 127];
        float pq = swsq[0][tid & 127] + swsq[1][tid & 127];
        float* pb = pstats + (size_t)blockIdx.x * 256;
        pb[tid] = ps;          // tid in 0..127
        pb[128 + tid] = pq;
    }

    // ---- Phase 4: quantize rows -> uint8 + scale. 4 threads per row. ----
    {
        int row4 = tid >> 2, t4 = tid & 3;   // rows 0..31
        int node = base + row4;
        const bf16_t* tp = tile + row4 * 136 + t4 * 32;
        bf16x8 v0 = *(const bf16x8*)(tp);
        bf16x8 v1 = *(const bf16x8*)(tp + 8);
        bf16x8 v2 = *(const bf16x8*)(tp + 16);
        bf16x8 v3 = *(const bf16x8*)(tp + 24);
        float am = 0.f;
#pragma unroll
        for (int k = 0; k < 8; ++k) {
            am = fmaxf(am, (float)v0[k]);
            am = fmaxf(am, (float)v1[k]);
            am = fmaxf(am, (float)v2[k]);
            am = fmaxf(am, (float)v3[k]);
        }
        am = fmaxf(am, __shfl_xor(am, 1));
        am = fmaxf(am, __shfl_xor(am, 2));
        float inv = am > 0.f ? 255.f / am : 0.f;
        if (t4 == 0) ysc[node] = am * (1.f / 255.f);
        u32 u[8];
        u[0] = pack4u((float)v0[0], (float)v0[1], (float)v0[2], (float)v0[3], inv);
        u[1] = pack4u((float)v0[4], (float)v0[5], (float)v0[6], (float)v0[7], inv);
        u[2] = pack4u((float)v1[0], (float)v1[1], (float)v1[2], (float)v1[3], inv);
        u[3] = pack4u((float)v1[4], (float)v1[5], (float)v1[6], (float)v1[7], inv);
        u[4] = pack4u((float)v2[0], (float)v2[1], (float)v2[2], (float)v2[3], inv);
        u[5] = pack4u((float)v2[4], (float)v2[5], (float)v2[6], (float)v2[7], inv);
        u[6] = pack4u((float)v3[0], (float)v3[1], (float)v3[2], (float)v3[3], inv);
        u[7] = pack4u((float)v3[4], (float)v3[5], (float)v3[6], (float)v3[7], inv);
        uint4* yp = (uint4*)(y8 + (size_t)node * DD + t4 * 32);
        yp[0] = make_uint4(u[0], u[1], u[2], u[3]);
        yp[1] = make_uint4(u[4], u[5], u[6], u[7]);
    }
}

// ---------------- pooling + head ----------------

// dequantizing segmented mean-pool, 2 nodes in flight per block
__global__ __launch_bounds__(256) void k_pool2u(
    const u8* __restrict__ y8, const float* __restrict__ ysc,
    const int* __restrict__ gstart,
    const float* __restrict__ scale, const float* __restrict__ shift,
    float* __restrict__ pooled)
{
    __shared__ float part[128];
    int g = blockIdx.x;
    int t = threadIdx.x;
    int f = t & 127, h = t >> 7;
    int s = gstart[g], e = gstart[g + 1];
    float acc = 0.f;
    for (int n = s + h; n < e; n += 2)
        acc += ysc[n] * (float)y8[(size_t)n * DD + f];
    if (h == 1) part[f] = acc;
    __syncthreads();
    if (h == 0) {
        acc += part[f];
        float cnt = (float)(e - s);
        float v = acc * scale[f] + cnt * shift[f];
        pooled[g * DD + f] = v / fmaxf(cnt, 1.0f);
    }
}

__global__ void k_head(const float* __restrict__ pooled,
                       const float* __restrict__ lin1w, const float* __restrict__ lin1b,
                       const float* __restrict__ lin2w, const float* __restrict__ lin2b,
                       float* __restrict__ out) {
    __shared__ float p[DD];
    __shared__ float h[DD];
    int g = blockIdx.x;
    int t = threadIdx.x;
    p[t] = pooled[g * DD + t];
    __syncthreads();
    float a = lin1b[t];
    for (int k = 0; k < DD; ++k) a += p[k] * lin1w[k * DD + t];
    h[t] = fmaxf(a, 0.f);
    __syncthreads();
    if (t < 10) {
        float o = lin2b[t];
        for (int k = 0; k < DD; ++k) o += h[k] * lin2w[k * 10 + t];
        out[g * 10 + t] = o;
    }
}

// ---------------- launch ----------------

extern "C" void kernel_launch(void* const* d_in, const int* in_sizes, int n_in,
                              void* d_out, int out_size, void* d_ws, size_t ws_size,
                              hipStream_t stream) {
    const float* x      = (const float*)d_in[0];
    const int*   ei     = (const int*)d_in[1];
    const int*   batch  = (const int*)d_in[2];
    const float* W1s    = (const float*)d_in[3];
    const float* b1s    = (const float*)d_in[4];
    const float* W2s    = (const float*)d_in[5];
    const float* b2s    = (const float*)d_in[6];
    const float* gammas = (const float*)d_in[7];
    const float* betas  = (const float*)d_in[8];
    const float* lin1w  = (const float*)d_in[9];
    const float* lin1b  = (const float*)d_in[10];
    const float* lin2w  = (const float*)d_in[11];
    const float* lin2b  = (const float*)d_in[12];
    float* out = (float*)d_out;

    char* p = (char*)d_ws;
    size_t off = 0;
    auto alloc = [&](size_t bytes) -> char* {
        char* r = p + off;
        off += (bytes + 255) & ~(size_t)255;
        return r;
    };
    int*    deg    = (int*)alloc(N_NODES * 4);
    size_t zero_bytes = off;
    int*    poffs  = (int*)alloc((N_NODES + 1) * 4);
    int*    cursor = (int*)alloc(N_NODES * 4);
    int*    bsum   = (int*)alloc(128 * 4);
    int*    bbase  = (int*)alloc(128 * 4);
    int*    csr    = (int*)alloc(((size_t)N_EDGES + 4 * N_NODES + 64) * 4); // pad-4 + slack
    u8*     x8s    = (u8*)alloc((size_t)N_NODES * DD);   // excess-128 input; q8b aliases it after L0
    u8*     q8a    = (u8*)alloc((size_t)N_NODES * DD);
    float*  sci    = (float*)alloc(N_NODES * 4);
    float*  sca    = (float*)alloc(N_NODES * 4);
    float*  scb    = (float*)alloc(N_NODES * 4);
    bf16_t* wshuf  = (bf16_t*)alloc(6 * 16384 * 2);
    float*  ss     = (float*)alloc(4 * 256 * 4);
    int*    gstart = (int*)alloc((N_GRAPHS + 1) * 4);
    float*  pooled = (float*)alloc(N_GRAPHS * DD * 4);
    float*  pstats = (float*)alloc((size_t)NTILES * 256 * 4);    // per-block partials
    float*  red    = (float*)alloc(RED_B * 256 * 4);             // stage-2 partials
    if (off > ws_size) return;

    // q8b reuses x8s's storage: x8s is only read by L0; q8b is written by L1
    // and read by L2 (stream-ordered on one stream, no overlap).
    u8* q8b = x8s;

    const int* srcA = ei;
    const int* dstA = ei + N_EDGES;

    k_zero<<<256, 256, 0, stream>>>((float4*)d_ws, (int)(zero_bytes / 16));
    k_hist8<<<1024, 256, 0, stream>>>(dstA, deg);
    k_scan1<<<SCAN_B, 1024, 0, stream>>>(deg, bsum);
    k_scan2<<<1, 128, 0, stream>>>(bsum, bbase, poffs);
    k_scan3<<<SCAN_B, 1024, 0, stream>>>(deg, bbase, poffs, cursor);
    k_fill8<<<1024, 256, 0, stream>>>(srcA, dstA, cursor, csr);
    k_pad<<<(N_NODES * 4 + 255) / 256, 256, 0, stream>>>(deg, poffs, csr);
    k_cvt8<<<1024, 256, 0, stream>>>(x, x8s, sci);
    k_shufw<<<(6 * 16384 + 255) / 256, 256, 0, stream>>>(W1s, W2s, wshuf);
    k_aff_init<<<1, 128, 0, stream>>>(ss);
    k_gbounds<<<(N_NODES + 255) / 256, 256, 0, stream>>>(batch, gstart);

    // L0: x8s (excess-128) -> q8a. L1: q8a -> q8b (aliases x8s). L2: q8b -> q8a.
    k_layer<true><<<NTILES, 128, 0, stream>>>(
        x8s, sci, q8a, sca, poffs, csr, deg,
        ss + 0 * 256, ss + 0 * 256 + 128,
        wshuf + 0 * 16384, wshuf + 1 * 16384,
        b1s + 0 * DD, b2s + 0 * DD, pstats);
    k_red<<<RED_B, 256, 0, stream>>>(pstats, red);
    k_aff_update<<<1, 128, 0, stream>>>(red, gammas + 0 * DD, betas + 0 * DD,
                                        ss + 1 * 256, ss + 1 * 256 + 128);

    k_layer<false><<<NTILES, 128, 0, stream>>>(
        q8a, sca, q8b, scb, poffs, csr, deg,
        ss + 1 * 256, ss + 1 * 256 + 128,
        wshuf + 2 * 16384, wshuf + 3 * 16384,
        b1s + 1 * DD, b2s + 1 * DD, pstats);
    k_red<<<RED_B, 256, 0, stream>>>(pstats, red);
    k_aff_update<<<1, 128, 0, stream>>>(red, gammas + 1 * DD, betas + 1 * DD,
                                        ss + 2 * 256, ss + 2 * 256 + 128);

    k_layer<false><<<NTILES, 128, 0, stream>>>(
        q8b, scb, q8a, sca, poffs, csr, deg,
        ss + 2 * 256, ss + 2 * 256 + 128,
        wshuf + 4 * 16384, wshuf + 5 * 16384,
        b1s + 2 * DD, b2s + 2 * DD, pstats);
    k_red<<<RED_B, 256, 0, stream>>>(pstats, red);
    k_aff_update<<<1, 128, 0, stream>>>(red, gammas + 2 * DD, betas + 2 * DD,
                                        ss + 3 * 256, ss + 3 * 256 + 128);

    k_pool2u<<<N_GRAPHS, 256, 0, stream>>>(q8a, sca, gstart,
                                           ss + 3 * 256, ss + 3 * 256 + 128, pooled);
    k_head<<<N_GRAPHS, 128, 0, stream>>>(pooled, lin1w, lin1b, lin2w, lin2b, out);
}

// Round 11
// 594.410 us; speedup vs baseline: 1.2756x; 1.1181x over previous
//
#include <hip/hip_runtime.h>
#include <hip/hip_bf16.h>

#define N_NODES 100000
#define N_EDGES 1600000
#define DD 128
#define N_GRAPHS 512
#define BN_EPS 1e-5f
#define NTILES 3125            // 3125*32 == 100000 exactly: no partial tiles
#define SCAN_B 98              // ceil(100000/1024)
#define RED_B 25               // 3125 = 25 * 125
#define PART_N 12500           // N_NODES / 8 (per-XCD node slice)

typedef unsigned int u32;
typedef unsigned char u8;
typedef __bf16 bf16_t;
typedef __bf16 bf16x2 __attribute__((ext_vector_type(2)));
typedef __bf16 bf16x4 __attribute__((ext_vector_type(4)));
typedef __bf16 bf16x8 __attribute__((ext_vector_type(8)));
typedef float f32x4 __attribute__((ext_vector_type(4)));

__device__ __forceinline__ u32 pack4u(float v0, float v1, float v2, float v3, float inv) {
    u32 q0 = (u32)fminf(rintf(v0 * inv), 255.f);
    u32 q1 = (u32)fminf(rintf(v1 * inv), 255.f);
    u32 q2 = (u32)fminf(rintf(v2 * inv), 255.f);
    u32 q3 = (u32)fminf(rintf(v3 * inv), 255.f);
    return q0 | (q1 << 8) | (q2 << 16) | (q3 << 24);
}

// ---------------- utility kernels ----------------

__global__ void k_zero(float4* p, int n) {
    float4 z = make_float4(0.f, 0.f, 0.f, 0.f);
    for (int i = blockIdx.x * blockDim.x + threadIdx.x; i < n; i += gridDim.x * blockDim.x)
        p[i] = z;
}

// XCD-partitioned histogram with NON-TEMPORAL edge reads: the streaming
// dst scan must not evict the deg lines being accumulated in L2.
__global__ void k_hist8(const int* __restrict__ dst, int* __restrict__ deg) {
    const int part = blockIdx.x & 7;
    const int lo = part * PART_N, hi = lo + PART_N;
    const int start = (blockIdx.x >> 3) * blockDim.x + threadIdx.x;
    const int stride = (gridDim.x >> 3) * blockDim.x;
    for (int e = start; e < N_EDGES; e += stride) {
        int d = __builtin_nontemporal_load(dst + e);
        if (d >= lo && d < hi) atomicAdd(&deg[d], 1);
    }
}

// hierarchical scan of padded degrees ((deg+3)&~3) -> poffs, cursor
__global__ void k_scan1(const int* __restrict__ deg, int* __restrict__ bsum) {
    __shared__ int sh[1024];
    int b = blockIdx.x, t = threadIdx.x;
    int i = b * 1024 + t;
    int pd = (i < N_NODES) ? ((deg[i] + 3) & ~3) : 0;
    sh[t] = pd;
    __syncthreads();
    for (int s = 512; s > 0; s >>= 1) {
        if (t < s) sh[t] += sh[t + s];
        __syncthreads();
    }
    if (t == 0) bsum[b] = sh[0];
}
__global__ void k_scan2(const int* __restrict__ bsum, int* __restrict__ bbase,
                        int* __restrict__ poffs) {
    __shared__ int sh[128];
    int t = threadIdx.x;
    int v = (t < SCAN_B) ? bsum[t] : 0;
    sh[t] = v;
    __syncthreads();
    for (int d = 1; d < 128; d <<= 1) {
        int o = (t >= d) ? sh[t - d] : 0;
        __syncthreads();
        sh[t] += o;
        __syncthreads();
    }
    if (t < SCAN_B) bbase[t] = sh[t] - v;          // exclusive base per block
    if (t == SCAN_B - 1) poffs[N_NODES] = sh[t];   // total padded edges
}
__global__ void k_scan3(const int* __restrict__ deg, const int* __restrict__ bbase,
                        int* __restrict__ poffs, int* __restrict__ cursor) {
    __shared__ int sh[1024];
    int b = blockIdx.x, t = threadIdx.x;
    int i = b * 1024 + t;
    int pd = (i < N_NODES) ? ((deg[i] + 3) & ~3) : 0;
    sh[t] = pd;
    __syncthreads();
    for (int d = 1; d < 1024; d <<= 1) {
        int o = (t >= d) ? sh[t - d] : 0;
        __syncthreads();
        sh[t] += o;
        __syncthreads();
    }
    if (i < N_NODES) {
        int off = bbase[b] + sh[t] - pd;
        poffs[i] = off; cursor[i] = off;
    }
}

// XCD-partitioned fill with NON-TEMPORAL dst/src reads. The streaming
// scan must not evict partially-filled csr lines from the 4MB per-XCD L2.
__global__ void k_fill8(const int* __restrict__ src, const int* __restrict__ dst,
                        int* __restrict__ cursor, int* __restrict__ csr) {
    const int part = blockIdx.x & 7;
    const int lo = part * PART_N, hi = lo + PART_N;
    const int start = (blockIdx.x >> 3) * blockDim.x + threadIdx.x;
    const int stride = (gridDim.x >> 3) * blockDim.x;
    for (int e = start; e < N_EDGES; e += stride) {
        int d = __builtin_nontemporal_load(dst + e);
        if (d >= lo && d < hi) {
            int s = __builtin_nontemporal_load(src + e);
            int pos = atomicAdd(&cursor[d], 1);
            csr[pos] = s;
        }
    }
}

// fill pad slots with the DEST node's own index; gather subtracts the
// overcount via the self-term coefficient (1 - #pads). Self line is L1-hot.
__global__ void k_pad(const int* __restrict__ deg, const int* __restrict__ poffs,
                      int* __restrict__ csr) {
    int t = blockIdx.x * blockDim.x + threadIdx.x;
    if (t >= N_NODES * 4) return;
    int n = t >> 2, j = t & 3;
    int s = poffs[n] + deg[n];
    if (s + j < poffs[n + 1]) csr[s + j] = n;
}

// Quantize the fp32 input to SIGNED i8 with per-row scale (127 levels).
// All three layers gather 128B rows. One wave per row: lane covers
// features (2*lane, 2*lane+1).
__global__ __launch_bounds__(256) void k_cvt8(const float* __restrict__ x,
                                              u8* __restrict__ x8,
                                              float* __restrict__ xsc) {
    int wid  = (blockIdx.x * blockDim.x + threadIdx.x) >> 6;
    int lane = threadIdx.x & 63;
    int nw   = (gridDim.x * blockDim.x) >> 6;
    for (int row = wid; row < N_NODES; row += nw) {
        float2 v = *(const float2*)(x + (size_t)row * DD + lane * 2);
        float am = fmaxf(fabsf(v.x), fabsf(v.y));
#pragma unroll
        for (int o = 32; o > 0; o >>= 1) am = fmaxf(am, __shfl_xor(am, o));
        float inv = am > 0.f ? 127.f / am : 0.f;
        int q0 = (int)rintf(fminf(fmaxf(v.x * inv, -127.f), 127.f));
        int q1 = (int)rintf(fminf(fmaxf(v.y * inv, -127.f), 127.f));
        u32 pk = ((u32)(q0 & 0xff)) | (((u32)(q1 & 0xff)) << 8);
        *(unsigned short*)(x8 + (size_t)row * DD + lane * 2) = (unsigned short)pk;
        if (lane == 0) xsc[row] = am * (1.f / 127.f);
    }
}

// Pre-shuffle the 6 weight matrices into exact MFMA B-fragment order (bf16).
__global__ void k_shufw(const float* __restrict__ W1s, const float* __restrict__ W2s,
                        bf16_t* __restrict__ wshuf) {
    int t = blockIdx.x * blockDim.x + threadIdx.x;
    if (t >= 6 * 16384) return;
    int g  = t >> 14;
    int r  = t & 16383;
    int j  = r & 7;
    int L  = (r >> 3) & 63;
    int nt = (r >> 9) & 7;
    int ks = r >> 12;
    int l  = g >> 1;
    const float* src = (g & 1) ? (W2s + l * 16384) : (W1s + l * 16384);
    int k = ks * 32 + (L >> 4) * 8 + j;
    int n = nt * 16 + (L & 15);
    wshuf[t] = (bf16_t)src[k * DD + n];
}

__global__ void k_aff_init(float* __restrict__ ss) {
    int f = threadIdx.x;
    if (f < DD) { ss[f] = 1.0f; ss[DD + f] = 0.0f; }
}

// stage-2 reduction of per-block partial stats: 25 blocks x 125 rows
__global__ void k_red(const float* __restrict__ pstats, float* __restrict__ red) {
    int b = blockIdx.x;            // 0..24
    int t = threadIdx.x;           // 0..255
    const float* p = pstats + (size_t)b * 125 * 256 + t;
    float acc = 0.f;
    for (int i = 0; i < 125; ++i) acc += p[i * 256];
    red[b * 256 + t] = acc;
}

__global__ void k_aff_update(const float* __restrict__ red, const float* __restrict__ gamma,
                             const float* __restrict__ beta, float* __restrict__ scale,
                             float* __restrict__ shift) {
    int f = threadIdx.x;
    if (f < DD) {
        float s = 0.f, q = 0.f;
        for (int i = 0; i < RED_B; ++i) {
            s += red[i * 256 + f];
            q += red[i * 256 + 128 + f];
        }
        float mu  = s * (1.0f / N_NODES);
        float var = q * (1.0f / N_NODES) - mu * mu;
        float inv = rsqrtf(var + BN_EPS);
        float sc  = gamma[f] * inv;
        scale[f] = sc;
        shift[f] = beta[f] - mu * sc;
    }
}

__global__ void k_gbounds(const int* __restrict__ batch, int* __restrict__ gstart) {
    int i = blockIdx.x * blockDim.x + threadIdx.x;
    if (i >= N_NODES) return;
    int b = batch[i];
    int bp = (i == 0) ? -1 : batch[i - 1];
    for (int g = bp + 1; g <= b; ++g) gstart[g] = i;
    if (i == N_NODES - 1)
        for (int g = b + 1; g <= N_GRAPHS; ++g) gstart[g] = N_NODES;
}

// ---------------- gather helpers (quarter-split: 4 edges / instruction) ----
// lane = (q4, l16); lane covers features l16*8 .. l16*8+7 of edge csr[e+q4].
// All rows are 128B quantized (i8 input for L0, u8 activations for L1/L2):
// uint2 (8B) per lane. SIGNED selects sign-extension on decode.

template<bool SIGNED>
__device__ __forceinline__ void load_row8(
    const u8* __restrict__ xg, int r, int l16, float (&v)[8])
{
    uint2 d = *(const uint2*)(xg + ((size_t)r << 7) + (l16 << 3));
    if (SIGNED) {
        v[0] = (float)(int)(signed char)(d.x & 0xffu);
        v[1] = (float)(int)(signed char)((d.x >> 8) & 0xffu);
        v[2] = (float)(int)(signed char)((d.x >> 16) & 0xffu);
        v[3] = (float)(int)(signed char)(d.x >> 24);
        v[4] = (float)(int)(signed char)(d.y & 0xffu);
        v[5] = (float)(int)(signed char)((d.y >> 8) & 0xffu);
        v[6] = (float)(int)(signed char)((d.y >> 16) & 0xffu);
        v[7] = (float)(int)(signed char)(d.y >> 24);
    } else {
        v[0] = (float)(d.x & 0xffu);
        v[1] = (float)((d.x >> 8) & 0xffu);
        v[2] = (float)((d.x >> 16) & 0xffu);
        v[3] = (float)(d.x >> 24);
        v[4] = (float)(d.y & 0xffu);
        v[5] = (float)((d.y >> 8) & 0xffu);
        v[6] = (float)((d.y >> 16) & 0xffu);
        v[7] = (float)(d.y >> 24);
    }
}

template<bool SIGNED>
__device__ __forceinline__ void acc_group(
    const u8* __restrict__ xg, const float* __restrict__ xsc,
    int r, int l16, float (&a)[8])
{
    float v[8];
    load_row8<SIGNED>(xg, r, l16, v);
    float s = xsc[r];
#pragma unroll
    for (int j = 0; j < 8; ++j) a[j] += s * v[j];
}

// ---------------- fused GIN layer ----------------
// R22 = REVERT to R18 (best measured: 596.9us total, L0 84us). Dual-node
// quarter-split gather, 1 group per node per iteration. The full lever
// ledger (R12-R21): waves null, instruction-count null, bytes -9%, deeper
// per-wave MLP negative in 3 forms -> the gather is pinned by the chip's
// random-128B-gather service path. This is the endpoint configuration.
template<bool SIGNED>
__global__ __launch_bounds__(128, 8) void k_layer(
    const u8* __restrict__ x8, const float* __restrict__ xsc,
    u8* __restrict__ y8, float* __restrict__ ysc,
    const int* __restrict__ poffs, const int* __restrict__ csr,
    const int* __restrict__ deg,
    const float* __restrict__ scale, const float* __restrict__ shift,
    const bf16_t* __restrict__ w1s, const bf16_t* __restrict__ w2s,
    const float* __restrict__ b1, const float* __restrict__ b2,
    float* __restrict__ pstats)
{
    __shared__ __align__(16) bf16_t tile[32 * 136];
    __shared__ float swsum[2][128];
    __shared__ float swsq[2][128];

    const int tid  = threadIdx.x;
    const int w    = tid >> 6;           // 0..1
    const int lane = tid & 63;
    const int base = blockIdx.x * 32;
    const int q4   = lane >> 4;          // quarter: which edge of the group
    const int l16  = lane & 15;          // feature octet within the row

    // ---- Phase 1: dual-node quarter-split gather -> LDS tile ----
    for (int rp = 0; rp < 8; ++rp) {
        const int rowA = (w << 4) + rp;  // rows 0..7 / 16..23
        const int rowB = rowA + 8;       // rows 8..15 / 24..31
        const int nA = base + rowA;
        const int nB = base + rowB;      // always < N_NODES (exact tiling)

        float aA[8] = {0.f, 0.f, 0.f, 0.f, 0.f, 0.f, 0.f, 0.f};
        float aB[8] = {0.f, 0.f, 0.f, 0.f, 0.f, 0.f, 0.f, 0.f};

        int eA = poffs[nA], eEA = poffs[nA + 1];
        int eB = poffs[nB], eEB = poffs[nB + 1];

        int rA = csr[eA + q4];
        int rB = csr[eB + q4];

        while ((eA < eEA) & (eB < eEB)) {
            int rA2 = csr[eA + 4 + q4];   // prefetch next groups (csr has slack)
            int rB2 = csr[eB + 4 + q4];
            acc_group<SIGNED>(x8, xsc, rA, l16, aA);
            acc_group<SIGNED>(x8, xsc, rB, l16, aB);
            rA = rA2; rB = rB2; eA += 4; eB += 4;
        }
        while (eA < eEA) {
            acc_group<SIGNED>(x8, xsc, rA, l16, aA);
            eA += 4; rA = csr[eA + q4];
        }
        while (eB < eEB) {
            acc_group<SIGNED>(x8, xsc, rB, l16, aB);
            eB += 4; rB = csr[eB + q4];
        }

        // self terms: one load instruction covers both selves (quarters 0/1)
        const int dgA = deg[nA], dgB = deg[nB];
        const float scoA = 1.f - (float)(((dgA + 3) & ~3) - dgA);
        const float scoB = 1.f - (float)(((dgB + 3) & ~3) - dgB);
        {
            int rs = (q4 & 1) ? nB : nA;
            float v[8];
            load_row8<SIGNED>(x8, rs, l16, v);
            float s = xsc[rs];
            float coA = (q4 == 0) ? scoA * s : 0.f;
            float coB = (q4 == 1) ? scoB * s : 0.f;
#pragma unroll
            for (int j = 0; j < 8; ++j) {
                aA[j] += coA * v[j];
                aB[j] += coB * v[j];
            }
        }

        // combine quarters: lanes l, l^16, l^32, l^48 hold same features
#pragma unroll
        for (int j = 0; j < 8; ++j) {
            aA[j] += __shfl_xor(aA[j], 16);
            aA[j] += __shfl_xor(aA[j], 32);
            aB[j] += __shfl_xor(aB[j], 16);
            aB[j] += __shfl_xor(aB[j], 32);
        }

        // BN-affine + write: lanes 0-15 write row A, lanes 16-31 write row B
        if (q4 < 2) {
            const bool selA = (q4 == 0);
            const float4 s0 = *(const float4*)(scale + (l16 << 3));
            const float4 s1 = *(const float4*)(scale + (l16 << 3) + 4);
            const float4 t0 = *(const float4*)(shift + (l16 << 3));
            const float4 t1 = *(const float4*)(shift + (l16 << 3) + 4);
            const float sarr[8] = {s0.x, s0.y, s0.z, s0.w, s1.x, s1.y, s1.z, s1.w};
            const float tarr[8] = {t0.x, t0.y, t0.z, t0.w, t1.x, t1.y, t1.z, t1.w};
            const float cnt = (float)((selA ? dgA : dgB) + 1);
            const int   row = selA ? rowA : rowB;
            bf16x8 pk;
#pragma unroll
            for (int j = 0; j < 8; ++j) {
                float av = selA ? aA[j] : aB[j];
                pk[j] = (bf16_t)(av * sarr[j] + cnt * tarr[j]);
            }
            *(bf16x8*)(&tile[row * 136 + (l16 << 3)]) = pk;
        }
    }
    __syncthreads();

    // ---- Phase 2: GEMM1 + bias + relu -> tile (reused) ----
    const int q = lane >> 4;
    const int c16 = lane & 15;
    const int arow = (w << 4) + c16;

    bf16x8 afr[4];
#pragma unroll
    for (int ks = 0; ks < 4; ++ks)
        afr[ks] = *(const bf16x8*)(&tile[arow * 136 + ks * 32 + q * 8]);
    __syncthreads();

    f32x4 acc[8];
#pragma unroll
    for (int nt = 0; nt < 8; ++nt) acc[nt] = (f32x4){0.f, 0.f, 0.f, 0.f};
#pragma unroll
    for (int ks = 0; ks < 4; ++ks) {
#pragma unroll
        for (int nt = 0; nt < 8; ++nt) {
            bf16x8 bfr = *(const bf16x8*)(w1s + (((ks << 3) + nt) * 64 + lane) * 8);
            acc[nt] = __builtin_amdgcn_mfma_f32_16x16x32_bf16(afr[ks], bfr, acc[nt], 0, 0, 0);
        }
    }
#pragma unroll
    for (int nt = 0; nt < 8; ++nt) {
        float bias = b1[(nt << 4) + c16];
#pragma unroll
        for (int i = 0; i < 4; ++i) {
            float v = fmaxf(acc[nt][i] + bias, 0.f);
            int row = (w << 4) + (q << 2) + i;
            tile[row * 136 + (nt << 4) + c16] = (bf16_t)v;
        }
    }
    __syncthreads();

    // ---- Phase 3: GEMM2 + bias + relu + BN partials -> tile ----
    bf16x8 afr2[4];
#pragma unroll
    for (int ks = 0; ks < 4; ++ks)
        afr2[ks] = *(const bf16x8*)(&tile[arow * 136 + ks * 32 + q * 8]);
    __syncthreads(); // tile overwritten below

#pragma unroll
    for (int nt = 0; nt < 8; ++nt) acc[nt] = (f32x4){0.f, 0.f, 0.f, 0.f};
#pragma unroll
    for (int ks = 0; ks < 4; ++ks) {
#pragma unroll
        for (int nt = 0; nt < 8; ++nt) {
            bf16x8 bfr = *(const bf16x8*)(w2s + (((ks << 3) + nt) * 64 + lane) * 8);
            acc[nt] = __builtin_amdgcn_mfma_f32_16x16x32_bf16(afr2[ks], bfr, acc[nt], 0, 0, 0);
        }
    }
#pragma unroll
    for (int nt = 0; nt < 8; ++nt) {
        float bias = b2[(nt << 4) + c16];
        float s1 = 0.f, s2 = 0.f;
#pragma unroll
        for (int i = 0; i < 4; ++i) {
            float v = fmaxf(acc[nt][i] + bias, 0.f);
            int row = (w << 4) + (q << 2) + i;
            s1 += v;
            s2 += v * v;
            tile[row * 136 + (nt << 4) + c16] = (bf16_t)v;
        }
        s1 += __shfl_down(s1, 32); s2 += __shfl_down(s2, 32);
        s1 += __shfl_down(s1, 16); s2 += __shfl_down(s2, 16);
        if (lane < 16) {
            swsum[w][(nt << 4) + lane] = s1;
            swsq[w][(nt << 4) + lane] = s2;
        }
    }
    __syncthreads();

    // per-block partial stats: plain coalesced stores (no atomics)
    {
        float ps = swsum[0][tid & 127] + swsum[1][tid & 127];
        float pq = swsq[0][tid & 127] + swsq[1][tid & 127];
        float* pb = pstats + (size_t)blockIdx.x * 256;
        pb[tid] = ps;          // tid in 0..127
        pb[128 + tid] = pq;
    }

    // ---- Phase 4: quantize rows -> uint8 + scale. 4 threads per row. ----
    {
        int row4 = tid >> 2, t4 = tid & 3;   // rows 0..31
        int node = base + row4;
        const bf16_t* tp = tile + row4 * 136 + t4 * 32;
        bf16x8 v0 = *(const bf16x8*)(tp);
        bf16x8 v1 = *(const bf16x8*)(tp + 8);
        bf16x8 v2 = *(const bf16x8*)(tp + 16);
        bf16x8 v3 = *(const bf16x8*)(tp + 24);
        float am = 0.f;
#pragma unroll
        for (int k = 0; k < 8; ++k) {
            am = fmaxf(am, (float)v0[k]);
            am = fmaxf(am, (float)v1[k]);
            am = fmaxf(am, (float)v2[k]);
            am = fmaxf(am, (float)v3[k]);
        }
        am = fmaxf(am, __shfl_xor(am, 1));
        am = fmaxf(am, __shfl_xor(am, 2));
        float inv = am > 0.f ? 255.f / am : 0.f;
        if (t4 == 0) ysc[node] = am * (1.f / 255.f);
        u32 u[8];
        u[0] = pack4u((float)v0[0], (float)v0[1], (float)v0[2], (float)v0[3], inv);
        u[1] = pack4u((float)v0[4], (float)v0[5], (float)v0[6], (float)v0[7], inv);
        u[2] = pack4u((float)v1[0], (float)v1[1], (float)v1[2], (float)v1[3], inv);
        u[3] = pack4u((float)v1[4], (float)v1[5], (float)v1[6], (float)v1[7], inv);
        u[4] = pack4u((float)v2[0], (float)v2[1], (float)v2[2], (float)v2[3], inv);
        u[5] = pack4u((float)v2[4], (float)v2[5], (float)v2[6], (float)v2[7], inv);
        u[6] = pack4u((float)v3[0], (float)v3[1], (float)v3[2], (float)v3[3], inv);
        u[7] = pack4u((float)v3[4], (float)v3[5], (float)v3[6], (float)v3[7], inv);
        uint4* yp = (uint4*)(y8 + (size_t)node * DD + t4 * 32);
        yp[0] = make_uint4(u[0], u[1], u[2], u[3]);
        yp[1] = make_uint4(u[4], u[5], u[6], u[7]);
    }
}

// ---------------- pooling + head ----------------

// dequantizing segmented mean-pool, 2 nodes in flight per block
__global__ __launch_bounds__(256) void k_pool2u(
    const u8* __restrict__ y8, const float* __restrict__ ysc,
    const int* __restrict__ gstart,
    const float* __restrict__ scale, const float* __restrict__ shift,
    float* __restrict__ pooled)
{
    __shared__ float part[128];
    int g = blockIdx.x;
    int t = threadIdx.x;
    int f = t & 127, h = t >> 7;
    int s = gstart[g], e = gstart[g + 1];
    float acc = 0.f;
    for (int n = s + h; n < e; n += 2)
        acc += ysc[n] * (float)y8[(size_t)n * DD + f];
    if (h == 1) part[f] = acc;
    __syncthreads();
    if (h == 0) {
        acc += part[f];
        float cnt = (float)(e - s);
        float v = acc * scale[f] + cnt * shift[f];
        pooled[g * DD + f] = v / fmaxf(cnt, 1.0f);
    }
}

__global__ void k_head(const float* __restrict__ pooled,
                       const float* __restrict__ lin1w, const float* __restrict__ lin1b,
                       const float* __restrict__ lin2w, const float* __restrict__ lin2b,
                       float* __restrict__ out) {
    __shared__ float p[DD];
    __shared__ float h[DD];
    int g = blockIdx.x;
    int t = threadIdx.x;
    p[t] = pooled[g * DD + t];
    __syncthreads();
    float a = lin1b[t];
    for (int k = 0; k < DD; ++k) a += p[k] * lin1w[k * DD + t];
    h[t] = fmaxf(a, 0.f);
    __syncthreads();
    if (t < 10) {
        float o = lin2b[t];
        for (int k = 0; k < DD; ++k) o += h[k] * lin2w[k * 10 + t];
        out[g * 10 + t] = o;
    }
}

// ---------------- launch ----------------

extern "C" void kernel_launch(void* const* d_in, const int* in_sizes, int n_in,
                              void* d_out, int out_size, void* d_ws, size_t ws_size,
                              hipStream_t stream) {
    const float* x      = (const float*)d_in[0];
    const int*   ei     = (const int*)d_in[1];
    const int*   batch  = (const int*)d_in[2];
    const float* W1s    = (const float*)d_in[3];
    const float* b1s    = (const float*)d_in[4];
    const float* W2s    = (const float*)d_in[5];
    const float* b2s    = (const float*)d_in[6];
    const float* gammas = (const float*)d_in[7];
    const float* betas  = (const float*)d_in[8];
    const float* lin1w  = (const float*)d_in[9];
    const float* lin1b  = (const float*)d_in[10];
    const float* lin2w  = (const float*)d_in[11];
    const float* lin2b  = (const float*)d_in[12];
    float* out = (float*)d_out;

    char* p = (char*)d_ws;
    size_t off = 0;
    auto alloc = [&](size_t bytes) -> char* {
        char* r = p + off;
        off += (bytes + 255) & ~(size_t)255;
        return r;
    };
    int*    deg    = (int*)alloc(N_NODES * 4);
    size_t zero_bytes = off;
    int*    poffs  = (int*)alloc((N_NODES + 1) * 4);
    int*    cursor = (int*)alloc(N_NODES * 4);
    int*    bsum   = (int*)alloc(128 * 4);
    int*    bbase  = (int*)alloc(128 * 4);
    int*    csr    = (int*)alloc(((size_t)N_EDGES + 4 * N_NODES + 64) * 4); // pad-4 + slack
    u8*     x8s    = (u8*)alloc((size_t)N_NODES * DD);   // i8 input; q8b aliases it after L0
    u8*     q8a    = (u8*)alloc((size_t)N_NODES * DD);
    float*  sci    = (float*)alloc(N_NODES * 4);
    float*  sca    = (float*)alloc(N_NODES * 4);
    float*  scb    = (float*)alloc(N_NODES * 4);
    bf16_t* wshuf  = (bf16_t*)alloc(6 * 16384 * 2);
    float*  ss     = (float*)alloc(4 * 256 * 4);
    int*    gstart = (int*)alloc((N_GRAPHS + 1) * 4);
    float*  pooled = (float*)alloc(N_GRAPHS * DD * 4);
    float*  pstats = (float*)alloc((size_t)NTILES * 256 * 4);    // per-block partials
    float*  red    = (float*)alloc(RED_B * 256 * 4);             // stage-2 partials
    if (off > ws_size) return;

    // q8b reuses x8s's storage: x8s is only read by L0; q8b is written by L1
    // and read by L2 (stream-ordered on one stream, no overlap).
    u8* q8b = x8s;

    const int* srcA = ei;
    const int* dstA = ei + N_EDGES;

    k_zero<<<256, 256, 0, stream>>>((float4*)d_ws, (int)(zero_bytes / 16));
    k_hist8<<<1024, 256, 0, stream>>>(dstA, deg);
    k_scan1<<<SCAN_B, 1024, 0, stream>>>(deg, bsum);
    k_scan2<<<1, 128, 0, stream>>>(bsum, bbase, poffs);
    k_scan3<<<SCAN_B, 1024, 0, stream>>>(deg, bbase, poffs, cursor);
    k_fill8<<<1024, 256, 0, stream>>>(srcA, dstA, cursor, csr);
    k_pad<<<(N_NODES * 4 + 255) / 256, 256, 0, stream>>>(deg, poffs, csr);
    k_cvt8<<<1024, 256, 0, stream>>>(x, x8s, sci);
    k_shufw<<<(6 * 16384 + 255) / 256, 256, 0, stream>>>(W1s, W2s, wshuf);
    k_aff_init<<<1, 128, 0, stream>>>(ss);
    k_gbounds<<<(N_NODES + 255) / 256, 256, 0, stream>>>(batch, gstart);

    // L0: x8s (i8) -> q8a. L1: q8a -> q8b (aliases x8s). L2: q8b -> q8a.
    k_layer<true><<<NTILES, 128, 0, stream>>>(
        x8s, sci, q8a, sca, poffs, csr, deg,
        ss + 0 * 256, ss + 0 * 256 + 128,
        wshuf + 0 * 16384, wshuf + 1 * 16384,
        b1s + 0 * DD, b2s + 0 * DD, pstats);
    k_red<<<RED_B, 256, 0, stream>>>(pstats, red);
    k_aff_update<<<1, 128, 0, stream>>>(red, gammas + 0 * DD, betas + 0 * DD,
                                        ss + 1 * 256, ss + 1 * 256 + 128);

    k_layer<false><<<NTILES, 128, 0, stream>>>(
        q8a, sca, q8b, scb, poffs, csr, deg,
        ss + 1 * 256, ss + 1 * 256 + 128,
        wshuf + 2 * 16384, wshuf + 3 * 16384,
        b1s + 1 * DD, b2s + 1 * DD, pstats);
    k_red<<<RED_B, 256, 0, stream>>>(pstats, red);
    k_aff_update<<<1, 128, 0, stream>>>(red, gammas + 1 * DD, betas + 1 * DD,
                                        ss + 2 * 256, ss + 2 * 256 + 128);

    k_layer<false><<<NTILES, 128, 0, stream>>>(
        q8b, scb, q8a, sca, poffs, csr, deg,
        ss + 2 * 256, ss + 2 * 256 + 128,
        wshuf + 4 * 16384, wshuf + 5 * 16384,
        b1s + 2 * DD, b2s + 2 * DD, pstats);
    k_red<<<RED_B, 256, 0, stream>>>(pstats, red);
    k_aff_update<<<1, 128, 0, stream>>>(red, gammas + 2 * DD, betas + 2 * DD,
                                        ss + 3 * 256, ss + 3 * 256 + 128);

    k_pool2u<<<N_GRAPHS, 256, 0, stream>>>(q8a, sca, gstart,
                                           ss + 3 * 256, ss + 3 * 256 + 128, pooled);
    k_head<<<N_GRAPHS, 128, 0, stream>>>(pooled, lin1w, lin1b, lin2w, lin2b, out);
}